// Round 9
// baseline (208.409 us; speedup 1.0000x reference)
//
#include <hip/hip_runtime.h>
#include <math.h>

// LongRangeProj forward, MI355X — DIAGNOSTIC ROUND (REP=10 amplification).
// Body identical to R8. The rep-loop launders tab2/acc through asm volatile so
// the compiler must re-execute loads+math each rep; fmax re-accumulation is
// idempotent so d_out is unchanged. Purpose: a single lrp_fwd dispatch must
// exceed the ~40 us poison-fill dispatches to surface in the top-5 counter
// table (it is per-dispatch!) and give us VALUBusy/Occupancy/FETCH for the
// real inner loop for the first time.

#define TWO_PI_F   6.28318530717958647692f
#define INV_2PI_F  0.15915494309189533577f
#define REP 10

__global__ __launch_bounds__(256) void lrp_geom(float2* __restrict__ tab2)
{
    const int idx = blockIdx.x * 256 + threadIdx.x;   // 0..14399
    if (idx >= 14400) return;
    const float dy = (float)(idx / 120 - 56);
    const float dx = (float)(idx % 120 - 56);
    const float fn = sqrtf(fmaf(dx, dx, dy * dy));    // exact 0 at (0,0)
    const float ph = atan2f(dy, dx);                  // setup only
    tab2[idx] = make_float2(fn, ph);
}

__global__ __launch_bounds__(256, 8) void lrp_fwd(
    const float* __restrict__ x,
    const float* __restrict__ rmean,
    const float* __restrict__ amean,
    const float* __restrict__ rstd,
    const float* __restrict__ astd,
    const float2* __restrict__ tab2,
    float* __restrict__ out)
{
    __shared__ float4 prm[64];   // {ln x, |rm|, theta_wrapped, 0} per node

    const int tid  = threadIdx.x;
    const int bc   = blockIdx.x >> 4;   // plane (b*64+c); 16 blocks per plane
    const int tile = blockIdx.x & 15;   // 256 pixels per block

    if (tid < 64) {
        const int idx = bc * 64 + tid;
        float th = amean[idx];
        th = fmaf(__builtin_rintf(th * INV_2PI_F), -TWO_PI_F, th); // -> [-pi,pi]
        prm[tid] = make_float4(logf(x[idx]), fabsf(rmean[idx]), th, 0.0f);
    }

    const int c = bc & 63;
    const float rs = rstd[c];
    const float as = astd[c];
    const float inv2rs = 1.0f / (2.0f * fmaf(rs, rs, 0.01f));
    const float inv2as = 1.0f / (2.0f * fmaf(as, as, 1e-4f));

    __syncthreads();

    const int pp  = tile * 256 + tid;   // pixel in plane, 0..4095
    const int wpx = pp & 63;
    const int hpx = pp >> 6;

    int baseRow[8];
    #pragma unroll
    for (int i = 0; i < 8; ++i)
        baseRow[i] = (hpx + 56 - 8 * i) * 120 + (wpx + 56);

    float acc = -INFINITY;

    #pragma unroll 1
    for (int rep = 0; rep < REP; ++rep) {
        const float2* tp = tab2;
        asm volatile("" : "+v"(tp));        // opaque ptr: no load CSE across reps
        asm volatile("" : "+v"(acc));       // opaque seed: no arith CSE

        #pragma unroll 2
        for (int i = 0; i < 8; ++i) {
            #pragma unroll
            for (int j = 0; j < 8; ++j) {
                const float4 q = prm[i * 8 + j];        // wave-uniform broadcast
                const float2 g = tp[baseRow[i] - 8 * j];// coalesced, L1/L2-hit
                const float d   = g.y - q.z;            // in [-2pi, 2pi]
                const float ang = fminf(fabsf(d), TWO_PI_F - fabsf(d));
                const float aa  = ang * ang;
                const float t   = g.x - q.y;
                const float arg = fmaf(-(t * t), inv2rs,
                                  fmaf(-aa, inv2as, q.x));
                acc = fmaxf(acc, arg);                  // idempotent across reps
            }
        }
    }

    if (((wpx & 7) | (hpx & 7)) == 0) {     // mask-point epilogue
        const float4 q = prm[(hpx >> 3) * 8 + (wpx >> 3)];
        acc = fmaxf(acc, fmaf(-(q.y * q.y), inv2rs, q.x));
    }

    out[bc * 4096 + pp] = __expf(acc);
}

extern "C" void kernel_launch(void* const* d_in, const int* in_sizes, int n_in,
                              void* d_out, int out_size, void* d_ws, size_t ws_size,
                              hipStream_t stream) {
    const float* x     = (const float*)d_in[0];
    const float* rmean = (const float*)d_in[1];
    const float* amean = (const float*)d_in[2];
    const float* rstd  = (const float*)d_in[3];
    const float* astd  = (const float*)d_in[4];
    float* out  = (float*)d_out;
    float2* tab2 = (float2*)d_ws;       // 115.2 KB scratch; rebuilt per call

    lrp_geom<<<57, 256, 0, stream>>>(tab2);
    lrp_fwd<<<2048, 256, 0, stream>>>(x, rmean, amean, rstd, astd, tab2, out);
}

// Round 10
// 72.610 us; speedup vs baseline: 2.8703x; 2.8703x over previous
//
#include <hip/hip_runtime.h>
#include <math.h>

// LongRangeProj forward, MI355X. B=2,C=64,NH=NW=8,H=W=64,STRIDE=8.
// term(n,p) = A_n + B_n*fn - fn^2*inv2rs - ang^2*inv2as,  out = exp(max_n term)
//   A = ln x - rm^2*inv2rs,  B = 2*rm*inv2rs   (per node, in LDS)
//   ang^2 = min(|d|, 2pi-|d|)^2 = d^2 + min(0, 4pi^2 - 4pi*|d|),  d = phi - theta_w
// Geometry table T4[dy+56][jp][wpx] (float4 = {fn,phi}x2 for j=2jp,2jp+1):
// 120*4*64*16B = 491 KB, L2-resident; one dwordx4 covers TWO terms, 16B/lane
// coalesced, jp folds into immediate offsets (one addr reg per i-row).
// Mask point (dx=dy=0): in-loop value <= A; center-pixel epilogue fmax(acc, A).

#define TWO_PI_F   6.28318530717958647692f
#define INV_2PI_F  0.15915494309189533577f
#define FOUR_PI_F  12.56637061435917295385f
#define FOUR_PI2_F 39.47841760435743447534f

__global__ __launch_bounds__(256) void lrp_geom(float4* __restrict__ tab4)
{
    const int idx = blockIdx.x * 256 + threadIdx.x;   // 0..30719
    const int wpx = idx & 63;
    const int jp  = (idx >> 6) & 3;
    const int dyi = idx >> 8;                         // 0..119
    const float dy  = (float)(dyi - 56);
    const float dxa = (float)(wpx - 16 * jp);         // j = 2*jp
    const float dxb = dxa - 8.0f;                     // j = 2*jp+1
    const float fna = sqrtf(fmaf(dxa, dxa, dy * dy));
    const float fnb = sqrtf(fmaf(dxb, dxb, dy * dy));
    const float pha = atan2f(dy, dxa);                // setup only; libm ok
    const float phb = atan2f(dy, dxb);
    tab4[idx] = make_float4(fna, pha, fnb, phb);
}

__global__ __launch_bounds__(256, 8) void lrp_fwd(
    const float* __restrict__ x,
    const float* __restrict__ rmean,
    const float* __restrict__ amean,
    const float* __restrict__ rstd,
    const float* __restrict__ astd,
    const float4* __restrict__ tab4,
    float* __restrict__ out)
{
    __shared__ float4 prm[64];   // {A, B, theta_wrapped, 0} per node

    const int tid  = threadIdx.x;
    const int bc   = blockIdx.x >> 4;   // plane (b*64+c); 16 blocks per plane
    const int tile = blockIdx.x & 15;   // 256 pixels per block

    const int c = bc & 63;
    const float rs = rstd[c];
    const float as = astd[c];
    const float inv2rs = 1.0f / (2.0f * fmaf(rs, rs, 0.01f));
    const float inv2as = 1.0f / (2.0f * fmaf(as, as, 1e-4f));

    if (tid < 64) {
        const int idx = bc * 64 + tid;
        const float lx = logf(x[idx]);
        const float rm = fabsf(rmean[idx]);
        float th = amean[idx];
        th = fmaf(__builtin_rintf(th * INV_2PI_F), -TWO_PI_F, th); // -> [-pi,pi]
        const float A = fmaf(-(rm * rm), inv2rs, lx);
        const float B = 2.0f * rm * inv2rs;
        prm[tid] = make_float4(A, B, th, 0.0f);
    }

    __syncthreads();

    const int pp  = tile * 256 + tid;   // pixel in plane, 0..4095
    const int wpx = pp & 63;
    const int hpx = pp >> 6;

    const float C0 = -inv2rs;
    const float C1 = -inv2as;

    float acc = -INFINITY;

    #pragma unroll
    for (int i = 0; i < 8; ++i) {
        // Row base: element ((hpx+56-8i)*4 + jp)*64 + wpx; jp => +64 elements
        const float4* rowp = tab4 + ((hpx + 56 - 8 * i) * 256 + wpx);
        #pragma unroll
        for (int jp = 0; jp < 4; ++jp) {
            const float4 g  = rowp[jp * 64];          // 2 terms per dwordx4
            const float4 qa = prm[i * 8 + 2 * jp];    // wave-uniform broadcast
            const float4 qb = prm[i * 8 + 2 * jp + 1];
            {   // term a: fn=g.x, phi=g.y
                const float d   = g.y - qa.z;
                const float aa  = fmaf(d, d,
                    fminf(0.0f, fmaf(-FOUR_PI_F, fabsf(d), FOUR_PI2_F)));
                const float mid = fmaf(g.x, fmaf(g.x, C0, qa.y), qa.x);
                acc = fmaxf(acc, fmaf(aa, C1, mid));
            }
            {   // term b: fn=g.z, phi=g.w
                const float d   = g.w - qb.z;
                const float aa  = fmaf(d, d,
                    fminf(0.0f, fmaf(-FOUR_PI_F, fabsf(d), FOUR_PI2_F)));
                const float mid = fmaf(g.z, fmaf(g.z, C0, qb.y), qb.x);
                acc = fmaxf(acc, fmaf(aa, C1, mid));
            }
        }
    }

    // Mask-point epilogue: center pixel's own-node term is exactly A (ang=0,
    // fn=0) and dominates the unfixed in-loop value (aa*inv2as >= 0).
    if (((wpx & 7) | (hpx & 7)) == 0) {
        acc = fmaxf(acc, prm[(hpx >> 3) * 8 + (wpx >> 3)].x);
    }

    out[bc * 4096 + pp] = __expf(acc);
}

extern "C" void kernel_launch(void* const* d_in, const int* in_sizes, int n_in,
                              void* d_out, int out_size, void* d_ws, size_t ws_size,
                              hipStream_t stream) {
    const float* x     = (const float*)d_in[0];
    const float* rmean = (const float*)d_in[1];
    const float* amean = (const float*)d_in[2];
    const float* rstd  = (const float*)d_in[3];
    const float* astd  = (const float*)d_in[4];
    float* out  = (float*)d_out;
    float4* tab4 = (float4*)d_ws;       // 491.5 KB scratch; rebuilt per call

    lrp_geom<<<120, 256, 0, stream>>>(tab4);
    // 128 planes x 16 blocks (256 px each) = 2048 blocks -> 8 waves/SIMD.
    lrp_fwd<<<2048, 256, 0, stream>>>(x, rmean, amean, rstd, astd, tab4, out);
}